// Round 1
// baseline (2560.978 us; speedup 1.0000x reference)
//
#include <hip/hip_runtime.h>
#include <cstddef>

#define S 64
#define VOL (64*64*64)      // 262144
#define CIN 32

__device__ __forceinline__ int iclamp(int v, int lo, int hi) {
    return v < lo ? lo : (v > hi ? hi : v);
}

// src[(co*32+ci)*27 + tap] -> dst[(tap*32+ci)*64 + co], co in [0,64)
__global__ void transpose_w_kernel(const float* __restrict__ src,
                                   float* __restrict__ dst) {
    int i = blockIdx.x * 256 + threadIdx.x;
    const int total = 64 * 32 * 27;
    if (i >= total) return;
    int tap = i % 27;
    int ci  = (i / 27) % 32;
    int co  = i / (27 * 32);
    dst[(tap * 32 + ci) * 64 + co] = src[i];
}

// Fused: 64-channel offset conv (channels 0..63 of w_off; 64..95 are dead
// because off_d = off_h in the reference) + trilinear grid sample.
// One thread per (b, d, h, w). Lanes consecutive in w -> coalesced conv loads.
__global__ __launch_bounds__(256)
void offconv_sample_kernel(const float* __restrict__ x,
                           const float* __restrict__ wt,   // [27][32][64]
                           float* __restrict__ sampled) {
    const int tid = threadIdx.x;
    const int p = blockIdx.x * 256 + tid;        // spatial index (d*64+h)*64+w
    const int b = blockIdx.y;
    const int w = p & 63;
    const int h = (p >> 6) & 63;
    const int d = p >> 12;

    const float* xb = x + (size_t)b * CIN * VOL;

    float acc[64];
#pragma unroll
    for (int i = 0; i < 64; ++i) acc[i] = 0.f;

    for (int kd = 0; kd < 3; ++kd) {
        const int zz = d + kd - 1;
        if (zz < 0 || zz >= S) continue;
        for (int kh = 0; kh < 3; ++kh) {
            const int yy = h + kh - 1;
            if (yy < 0 || yy >= S) continue;
            for (int kw = 0; kw < 3; ++kw) {
                const int xx = w + kw - 1;
                const bool okx = (xx >= 0) && (xx < S);
                const int tap = (kd * 3 + kh) * 3 + kw;
                const float* __restrict__ wtap = wt + tap * 32 * 64;
                const float* __restrict__ xp = xb + (size_t)(zz * 64 + yy) * 64 + xx;
                for (int ci = 0; ci < CIN; ++ci) {
                    const float xv = okx ? xp[(size_t)ci * VOL] : 0.f;
                    const float* __restrict__ wrow = wtap + ci * 64;
#pragma unroll
                    for (int co = 0; co < 64; ++co)
                        acc[co] = fmaf(xv, wrow[co], acc[co]);
                }
            }
        }
    }

    // Trilinear sampling. Reference (with its faithful bugs) reduces to:
    //   ix (W axis) = off_h*31.5 + d
    //   iy (H axis) = off_w*31.5 + h
    //   iz (D axis) = off_h*31.5 + w
    const float fd = (float)d, fh = (float)h, fw = (float)w;
    for (int c = 0; c < CIN; ++c) {
        const float offw = acc[c]      * 31.5f;
        const float offh = acc[32 + c] * 31.5f;
        const float ix = offh + fd;
        const float iy = offw + fh;
        const float iz = offh + fw;
        const float x0f = floorf(ix), y0f = floorf(iy), z0f = floorf(iz);
        const float tx = ix - x0f, ty = iy - y0f, tz = iz - z0f;
        const int ix0 = (int)x0f, iy0 = (int)y0f, iz0 = (int)z0f;
        const float* __restrict__ v = xb + (size_t)c * VOL;
        float out = 0.f;
#pragma unroll
        for (int dz = 0; dz < 2; ++dz) {
#pragma unroll
            for (int dy = 0; dy < 2; ++dy) {
#pragma unroll
                for (int dx = 0; dx < 2; ++dx) {
                    const int xc = ix0 + dx, yc = iy0 + dy, zc = iz0 + dz;
                    const bool inb = ((unsigned)xc < 64u) && ((unsigned)yc < 64u)
                                  && ((unsigned)zc < 64u);
                    const float wgt = (dx ? tx : 1.f - tx)
                                    * (dy ? ty : 1.f - ty)
                                    * (dz ? tz : 1.f - tz);
                    const int xcc = iclamp(xc, 0, 63);
                    const int ycc = iclamp(yc, 0, 63);
                    const int zcc = iclamp(zc, 0, 63);
                    const float val = v[(zcc * 64 + ycc) * 64 + xcc];
                    out += inb ? wgt * val : 0.f;
                }
            }
        }
        sampled[((size_t)(b * 32 + c)) * VOL + p] = out;
    }
}

// Final 3x3x3 conv: sampled (B,32,S,S,S) -> out (B,64,S,S,S), + bias.
__global__ __launch_bounds__(256)
void regconv_kernel(const float* __restrict__ sm,
                    const float* __restrict__ wt,    // [27][32][64]
                    const float* __restrict__ bias,
                    float* __restrict__ out) {
    const int tid = threadIdx.x;
    const int p = blockIdx.x * 256 + tid;
    const int b = blockIdx.y;
    const int w = p & 63;
    const int h = (p >> 6) & 63;
    const int d = p >> 12;

    const float* smb = sm + (size_t)b * CIN * VOL;

    float acc[64];
#pragma unroll
    for (int i = 0; i < 64; ++i) acc[i] = 0.f;

    for (int kd = 0; kd < 3; ++kd) {
        const int zz = d + kd - 1;
        if (zz < 0 || zz >= S) continue;
        for (int kh = 0; kh < 3; ++kh) {
            const int yy = h + kh - 1;
            if (yy < 0 || yy >= S) continue;
            for (int kw = 0; kw < 3; ++kw) {
                const int xx = w + kw - 1;
                const bool okx = (xx >= 0) && (xx < S);
                const int tap = (kd * 3 + kh) * 3 + kw;
                const float* __restrict__ wtap = wt + tap * 32 * 64;
                const float* __restrict__ xp = smb + (size_t)(zz * 64 + yy) * 64 + xx;
                for (int ci = 0; ci < CIN; ++ci) {
                    const float xv = okx ? xp[(size_t)ci * VOL] : 0.f;
                    const float* __restrict__ wrow = wtap + ci * 64;
#pragma unroll
                    for (int co = 0; co < 64; ++co)
                        acc[co] = fmaf(xv, wrow[co], acc[co]);
                }
            }
        }
    }

#pragma unroll
    for (int co = 0; co < 64; ++co) {
        out[((size_t)(b * 64 + co)) * VOL + p] = acc[co] + bias[co];
    }
}

extern "C" void kernel_launch(void* const* d_in, const int* in_sizes, int n_in,
                              void* d_out, int out_size, void* d_ws, size_t ws_size,
                              hipStream_t stream) {
    (void)in_sizes; (void)n_in; (void)out_size; (void)ws_size;
    const float* x     = (const float*)d_in[0];   // (2,32,64,64,64)
    const float* w_off = (const float*)d_in[1];   // (96,32,3,3,3)
    const float* w_reg = (const float*)d_in[2];   // (64,32,3,3,3)
    const float* b_reg = (const float*)d_in[3];   // (64,)
    float* out = (float*)d_out;                   // (2,64,64,64,64)

    float* sampled = (float*)d_ws;                // 2*32*VOL floats = 64 MiB
    float* w_off_t = sampled + (size_t)2 * 32 * VOL;
    float* w_reg_t = w_off_t + 27 * 32 * 64;

    const int wtotal = 64 * 32 * 27;
    transpose_w_kernel<<<(wtotal + 255) / 256, 256, 0, stream>>>(w_off, w_off_t);
    transpose_w_kernel<<<(wtotal + 255) / 256, 256, 0, stream>>>(w_reg, w_reg_t);

    dim3 grid(VOL / 256, 2);
    offconv_sample_kernel<<<grid, 256, 0, stream>>>(x, w_off_t, sampled);
    regconv_kernel<<<grid, 256, 0, stream>>>(sampled, w_reg_t, b_reg, out);
}

// Round 3
// 1006.558 us; speedup vs baseline: 2.5443x; 2.5443x over previous
//
#include <hip/hip_runtime.h>
#include <cstddef>

#define S 64
#define VOL (64*64*64)      // 262144
#define CIN 32

typedef __attribute__((ext_vector_type(8))) short bf16x8;
typedef __attribute__((ext_vector_type(4))) float floatx4;

__device__ __forceinline__ unsigned short f2bf(float f) {
    union { float f; unsigned u; } v; v.f = f;
    unsigned r = v.u + 0x7fffu + ((v.u >> 16) & 1u);   // RNE
    return (unsigned short)(r >> 16);
}
__device__ __forceinline__ float bf2f(unsigned short h) {
    union { unsigned u; float f; } v; v.u = ((unsigned)h) << 16;
    return v.f;
}
__device__ __forceinline__ int iclamp(int v, int lo, int hi) {
    return v < lo ? lo : (v > hi ? hi : v);
}

__device__ __forceinline__ unsigned short load_bf16bits(const float* p)          { return f2bf(*p); }
__device__ __forceinline__ unsigned short load_bf16bits(const unsigned short* p) { return *p; }

// Weight prep: src [co][ci][27] fp32 -> dst [tap][co][ci] bf16 (co<64).
__global__ void prep_w_kernel(const float* __restrict__ w_off,
                              const float* __restrict__ w_reg,
                              unsigned short* __restrict__ wt1,
                              unsigned short* __restrict__ wt2) {
    int i = blockIdx.x * 256 + threadIdx.x;   // i = tap*2048 + co*32 + ci
    if (i >= 27 * 64 * 32) return;
    int ci = i & 31;
    int co = (i >> 5) & 63;
    int tap = i >> 11;
    wt1[i] = f2bf(w_off[(co * 32 + ci) * 27 + tap]);
    wt2[i] = f2bf(w_reg[(co * 32 + ci) * 27 + tap]);
}

// Implicit-GEMM 3x3x3 conv via MFMA 16x16x32 bf16.
// Workgroup: 256 thr = 4 waves; output tile 64co x 128pos (d fixed, h0..h0+1, all w).
// LDS tile: [zz 0..2][yy 0..3][w' 0..65][ci 0..31] bf16, pitch 80 B (40 ushort).
// A-frag (weights): lane holds W[co = base+(lane&15)][ci = (lane>>4)*8 + j].
// B-frag (input):   lane holds X[ci = (lane>>4)*8 + j][pos = base+(lane&15)].
// C/D: col(=pos)=lane&15, row(=co)=(lane>>4)*4+reg  [measured m89/m91].
template <typename TIN, bool WRITE_BF16>
__global__ __launch_bounds__(256)
void conv_mfma_kernel(const TIN* __restrict__ src,            // [B][32][VOL]
                      const unsigned short* __restrict__ wt,  // [27][64][32] bf16
                      const float* __restrict__ bias,         // used when !WRITE_BF16
                      void* __restrict__ dstv) {              // [B][64][VOL]
    __shared__ unsigned short lds[792 * 40];   // 63,360 B

    const int d  = blockIdx.x;
    const int h0 = blockIdx.y * 2;
    const int b  = blockIdx.z;
    const int t  = threadIdx.x;

    const TIN* sb = src + (size_t)b * CIN * VOL;

    // ---- stage input halo: 792 rows x 32 ci = 25344 elems, 99 per thread ----
    for (int i = 0; i < 99; ++i) {
        int f = t + i * 256;
        int row = f / 66;               // (zz*4+yy)*32 + ci
        int wp  = f - row * 66;         // w' in 0..65
        int ci  = row & 31;
        int zy  = row >> 5;             // zz*4+yy
        int zz  = zy >> 2;
        int yy  = zy & 3;
        int z = d + zz - 1;
        int y = h0 + yy - 1;
        int xx = wp - 1;
        unsigned short v = 0;
        if ((unsigned)z < 64u && (unsigned)y < 64u && (unsigned)xx < 64u)
            v = load_bf16bits(sb + (size_t)ci * VOL + (z * 64 + y) * 64 + xx);
        lds[(zy * 66 + wp) * 40 + ci] = v;
    }
    __syncthreads();

    const int lane = t & 63;
    const int wv   = t >> 6;        // wave id: pos subrange [wv*32, wv*32+32)
    const int l15  = lane & 15;
    const int quad = lane >> 4;

    floatx4 acc[2][4];
#pragma unroll
    for (int nt = 0; nt < 2; ++nt)
#pragma unroll
        for (int mt = 0; mt < 4; ++mt)
#pragma unroll
            for (int r = 0; r < 4; ++r) acc[nt][mt][r] = 0.f;

#pragma unroll
    for (int tap = 0; tap < 27; ++tap) {
        const int kd = tap / 9;
        const int kh = (tap % 9) / 3;
        const int kw = tap % 3;
        bf16x8 bfr[2];
#pragma unroll
        for (int nt = 0; nt < 2; ++nt) {
            const int pbase = wv * 32 + nt * 16;
            const int hh = pbase >> 6;            // 0 or 1
            const int wb = pbase & 63;
            const int ldsrow = (kd * 4 + hh + kh) * 66 + (wb + kw + l15);
            bfr[nt] = *(const bf16x8*)&lds[ldsrow * 40 + quad * 8];
        }
#pragma unroll
        for (int mt = 0; mt < 4; ++mt) {
            bf16x8 afr = *(const bf16x8*)&wt[((tap * 64) + mt * 16 + l15) * 32 + quad * 8];
            acc[0][mt] = __builtin_amdgcn_mfma_f32_16x16x32_bf16(afr, bfr[0], acc[0][mt], 0, 0, 0);
            acc[1][mt] = __builtin_amdgcn_mfma_f32_16x16x32_bf16(afr, bfr[1], acc[1][mt], 0, 0, 0);
        }
    }

    // ---- epilogue ----
#pragma unroll
    for (int nt = 0; nt < 2; ++nt) {
        const int pbase = wv * 32 + nt * 16;
        const int hh = pbase >> 6;
        const int wb = pbase & 63;
        const int pos = d * 4096 + (h0 + hh) * 64 + wb + l15;
#pragma unroll
        for (int mt = 0; mt < 4; ++mt) {
#pragma unroll
            for (int r = 0; r < 4; ++r) {
                const int co = mt * 16 + quad * 4 + r;
                const size_t oidx = ((size_t)(b * 64 + co)) * VOL + pos;
                const float v = acc[nt][mt][r];
                if (WRITE_BF16) {
                    ((unsigned short*)dstv)[oidx] = f2bf(v);
                } else {
                    ((float*)dstv)[oidx] = v + bias[co];
                }
            }
        }
    }
}

// Trilinear gather. Tile: (b, c, h) fixed; 16 d x 16 w. Lanes d-fastest for
// coalesced x reads (sample coords: ix~d is the contiguous axis); LDS 16x16
// transpose so sampled writes are w-coalesced.
__global__ __launch_bounds__(256)
void gather_kernel(const float* __restrict__ x,
                   const unsigned short* __restrict__ off,   // [B][64][VOL] bf16
                   unsigned short* __restrict__ sampled) {   // [B][32][VOL] bf16
    __shared__ float res[16][17];

    const int bx = blockIdx.x;          // wt4 + 4*dt + 16*h
    const int wt4 = bx & 3;
    const int dt  = (bx >> 2) & 3;
    const int h   = bx >> 4;
    const int c = blockIdx.y;
    const int b = blockIdx.z;
    const int t = threadIdx.x;
    const int d_i = t & 15;
    const int w_i = t >> 4;
    const int d = dt * 16 + d_i;
    const int w = wt4 * 16 + w_i;
    const int p = d * 4096 + h * 64 + w;

    const float* vol = x + ((size_t)(b * CIN + c)) * VOL;
    const float offw = bf2f(off[((size_t)(b * 64 + c)) * VOL + p]);
    const float offh = bf2f(off[((size_t)(b * 64 + 32 + c)) * VOL + p]);

    // Faithful-bug mapping: ix = off_h*31.5 + d, iy = off_w*31.5 + h, iz = off_h*31.5 + w
    const float ix = offh * 31.5f + (float)d;
    const float iy = offw * 31.5f + (float)h;
    const float iz = offh * 31.5f + (float)w;

    const float x0f = floorf(ix), y0f = floorf(iy), z0f = floorf(iz);
    const float tx = ix - x0f, ty = iy - y0f, tz = iz - z0f;
    const int ix0 = (int)x0f, iy0 = (int)y0f, iz0 = (int)z0f;

    float out = 0.f;
#pragma unroll
    for (int dz = 0; dz < 2; ++dz) {
#pragma unroll
        for (int dy = 0; dy < 2; ++dy) {
#pragma unroll
            for (int dx = 0; dx < 2; ++dx) {
                const int xc = ix0 + dx, yc = iy0 + dy, zc = iz0 + dz;
                const bool inb = ((unsigned)xc < 64u) && ((unsigned)yc < 64u)
                              && ((unsigned)zc < 64u);
                const float wgt = (dx ? tx : 1.f - tx)
                                * (dy ? ty : 1.f - ty)
                                * (dz ? tz : 1.f - tz);
                const int xcc = iclamp(xc, 0, 63);
                const int ycc = iclamp(yc, 0, 63);
                const int zcc = iclamp(zc, 0, 63);
                const float val = vol[(zcc * 64 + ycc) * 64 + xcc];
                out += inb ? wgt * val : 0.f;
            }
        }
    }

    res[w_i][d_i] = out;
    __syncthreads();

    const int w_o = t & 15;
    const int d_o = t >> 4;
    sampled[((size_t)(b * CIN + c)) * VOL + (dt * 16 + d_o) * 4096 + h * 64
            + wt4 * 16 + w_o] = f2bf(res[w_o][d_o]);
}

extern "C" void kernel_launch(void* const* d_in, const int* in_sizes, int n_in,
                              void* d_out, int out_size, void* d_ws, size_t ws_size,
                              hipStream_t stream) {
    (void)in_sizes; (void)n_in; (void)out_size; (void)ws_size;
    const float* x     = (const float*)d_in[0];   // (2,32,64,64,64)
    const float* w_off = (const float*)d_in[1];   // (96,32,3,3,3)
    const float* w_reg = (const float*)d_in[2];   // (64,32,3,3,3)
    const float* b_reg = (const float*)d_in[3];   // (64,)
    float* out = (float*)d_out;                   // (2,64,64,64,64)

    // ws: offsets bf16 (64 MiB) | sampled bf16 (32 MiB) | wt1 | wt2
    unsigned short* off     = (unsigned short*)d_ws;
    unsigned short* sampled = off + (size_t)2 * 64 * VOL;
    unsigned short* wt1     = sampled + (size_t)2 * CIN * VOL;
    unsigned short* wt2     = wt1 + 27 * 64 * 32;

    prep_w_kernel<<<216, 256, 0, stream>>>(w_off, w_reg, wt1, wt2);

    dim3 cgrid(64, 32, 2);
    conv_mfma_kernel<float, true><<<cgrid, 256, 0, stream>>>(x, wt1, nullptr, (void*)off);

    dim3 ggrid(1024, 32, 2);
    gather_kernel<<<ggrid, 256, 0, stream>>>(x, off, sampled);

    conv_mfma_kernel<unsigned short, false><<<cgrid, 256, 0, stream>>>(sampled, wt2, b_reg, (void*)out);
}